// Round 5
// baseline (204.690 us; speedup 1.0000x reference)
//
#include <hip/hip_runtime.h>
#include <hip/hip_bf16.h>

typedef unsigned short u16;
typedef unsigned int   u32;
typedef __bf16 bf16x8 __attribute__((ext_vector_type(8)));
typedef float  f32x4  __attribute__((ext_vector_type(4)));

#define BB 2
#define TT 8192
#define DD 512
#define HH 8
#define WW 256
#define DH 64
#define NX 8388608   // 16384*512
#define NW 262144    // 512*512

__device__ __forceinline__ float b2f(u16 u) {
    unsigned int x = ((unsigned int)u) << 16;
    return __builtin_bit_cast(float, x);
}
__device__ __forceinline__ u16 f2b(float f) {
    __bf16 h = (__bf16)f;
    return __builtin_bit_cast(u16, h);
}
__device__ __forceinline__ bf16x8 ldsfrag(const u16* p) {
    return *(const bf16x8*)p;
}
__device__ __forceinline__ f32x4 mfma16(bf16x8 a, bf16x8 b, f32x4 c) {
    return __builtin_amdgcn_mfma_f32_16x16x32_bf16(a, b, c, 0, 0, 0);
}

typedef __attribute__((address_space(1))) u32 gu32;
typedef __attribute__((address_space(3))) u32 lu32;
// async global->LDS, 16B per lane, dest = wave-uniform base + lane*16
__device__ __forceinline__ void gl_lds(const u16* g, u16* l) {
    __builtin_amdgcn_global_load_lds((gu32*)g, (lu32*)l, 16, 0, 0);
}

// ---- convert all 9 inputs to bf16 in workspace (vectorized, 8 elem/thread).
// dtype flag computed per-block from x's first 2048 u16 (deterministic);
// block 0 persists it for the O-proj epilogue.
__device__ __forceinline__ void cvt8(const void* s, u16* d, long i, int f) {
    if (f) {
        const u32* sp = (const u32*)s + i;
        uint4 a = *(const uint4*)(sp);
        uint4 b = *(const uint4*)(sp + 4);
        u16 o[8];
        o[0] = f2b(__builtin_bit_cast(float, a.x));
        o[1] = f2b(__builtin_bit_cast(float, a.y));
        o[2] = f2b(__builtin_bit_cast(float, a.z));
        o[3] = f2b(__builtin_bit_cast(float, a.w));
        o[4] = f2b(__builtin_bit_cast(float, b.x));
        o[5] = f2b(__builtin_bit_cast(float, b.y));
        o[6] = f2b(__builtin_bit_cast(float, b.z));
        o[7] = f2b(__builtin_bit_cast(float, b.w));
        *(uint4*)(d + i) = *(const uint4*)o;
    } else {
        *(uint4*)(d + i) = *(const uint4*)((const u16*)s + i);
    }
}

__global__ void convert_all(const void* x, const void* Wq, const void* bq,
                            const void* Wk, const void* bk, const void* Wv,
                            const void* bv, const void* Wo, const void* bo,
                            u16* __restrict__ xb, u16* __restrict__ Wcat,
                            u16* __restrict__ Wob, u16* __restrict__ bcat,
                            u16* __restrict__ bob, int* __restrict__ flagw)
{
    __shared__ int sflag;
    const int tid = threadIdx.x;
    if (tid == 0) sflag = 0;
    __syncthreads();
    int mybad = 0;
    for (int i = tid; i < 2048; i += 256) {
        float v = b2f(((const u16*)x)[i]);
        if (!(fabsf(v) < 100.f)) mybad = 1;   // fp32 mantissa halves look wild
    }
    if (mybad) atomicOr(&sflag, 1);
    __syncthreads();
    const int f = sflag ? 1 : 0;
    if (blockIdx.x == 0 && tid == 0) *flagw = f;

    long i = ((long)blockIdx.x * 256 + tid) * 8;
    if (i < NX)            { cvt8(x,  xb,           i, f); return; }
    i -= NX;
    if (i < NW)            { cvt8(Wq, Wcat,         i, f); return; }
    i -= NW;
    if (i < NW)            { cvt8(Wk, Wcat + NW,    i, f); return; }
    i -= NW;
    if (i < NW)            { cvt8(Wv, Wcat + 2*NW,  i, f); return; }
    i -= NW;
    if (i < NW)            { cvt8(Wo, Wob,          i, f); return; }
    i -= NW;
    if (i < 512)           { cvt8(bq, bcat,         i, f); return; }
    i -= 512;
    if (i < 512)           { cvt8(bk, bcat + 512,   i, f); return; }
    i -= 512;
    if (i < 512)           { cvt8(bv, bcat + 1024,  i, f); return; }
    i -= 512;
    if (i < 512)           { cvt8(bo, bob,          i, f); }
}

// 128x128-tile GEMM, K=512. Round-6: T4 counted-vmcnt 3-buffer ring.
// Round-5 post-mortem: 2-deep double-buffer still drains vmcnt(0) at every
// barrier (prefetch must land within one ~155cy MFMA phase vs 300-900cy
// latency) and 64KB LDS halved occupancy (18.6%). Now: BK=32, 3 buffers
// (48KB -> 3 blk/CU), iteration t stages tile t+2, computes tile t, then
// s_waitcnt vmcnt(4) + raw s_barrier: tile t+1 ready, tile t+2's 4 loads
// REMAIN IN FLIGHT across the barrier (never drain to 0 in the loop - T4).
// sched_barrier(0) after each barrier stops hipcc hoisting next ds_reads.
// out[m,n] = sum_k A[m,k]*Bw[n,k] + bias[n].
// mode 0 (fused QKV, N=1536): seg0->out0 (Q [t][h*64+d]), seg1->out1 (K same),
//   seg2->out2 (V TRANSPOSED: [(b*8+h)*64+d][t]).
// mode 1 (O-proj): out0, fp32 if *flagp else bf16.
__global__ __launch_bounds__(256, 3)
void gemm128(const u16* __restrict__ A, const u16* __restrict__ Bw,
             const u16* __restrict__ bias, void* __restrict__ out0,
             u16* __restrict__ out1, u16* __restrict__ out2,
             int mode, const int* __restrict__ flagp)
{
    __shared__ __align__(16) u16 AsF[3][128 * 32];   // 3 x 8 KB
    __shared__ __align__(16) u16 BsF[3][128 * 32];   // 3 x 8 KB (48 KB total)

    const int tid  = threadIdx.x;
    const int lane = tid & 63;
    const int wv   = tid >> 6;
    const int col  = lane & 15;
    const int quad = lane >> 4;
    const int wm   = (wv & 1) * 64;
    const int wn   = (wv >> 1) * 64;
    const int m0   = blockIdx.x * 128;
    const int n0   = blockIdx.y * 128;

    f32x4 acc[4][4] = {};

    // staging: per wave 2 gl_lds for A + 2 for B (1KB each, 16 rows x 64B).
    // lane l -> row group*16 + (l>>2), 16B col-block l&3; source col-block
    // XOR-swizzled by (row&3) so the read side (quad ^ (col&3)) is spread.
    const int srow = lane >> 2;
    const int scol = lane & 3;

    auto STAGE = [&](int buf, int k0) {
        #pragma unroll
        for (int i = 0; i < 2; i++) {
            const int r  = wv * 32 + i * 16 + srow;
            const int cb = scol ^ (r & 3);
            gl_lds(A  + (size_t)(m0 + r) * 512 + k0 + cb * 8, &AsF[buf][(wv * 2 + i) * 512]);
            gl_lds(Bw + (size_t)(n0 + r) * 512 + k0 + cb * 8, &BsF[buf][(wv * 2 + i) * 512]);
        }
    };

    const int rdo = (quad ^ (col & 3)) * 8;   // swizzled 16B slot within 64B row

    // prologue: tiles 0,1 in flight; wait for tile 0 only (4 loads stay out)
    STAGE(0, 0);
    STAGE(1, 32);
    asm volatile("s_waitcnt vmcnt(4) lgkmcnt(0)" ::: "memory");
    __builtin_amdgcn_s_barrier();
    __builtin_amdgcn_sched_barrier(0);

    int cur = 0;
    for (int t = 0; t < 14; t++) {
        const int stg = (cur == 0) ? 2 : cur - 1;     // (cur+2)%3
        STAGE(stg, (t + 2) * 32);
        bf16x8 fa[4], fb[4];
        #pragma unroll
        for (int mi = 0; mi < 4; mi++)
            fa[mi] = ldsfrag(&AsF[cur][(wm + mi * 16 + col) * 32 + rdo]);
        #pragma unroll
        for (int ni = 0; ni < 4; ni++)
            fb[ni] = ldsfrag(&BsF[cur][(wn + ni * 16 + col) * 32 + rdo]);
        #pragma unroll
        for (int mi = 0; mi < 4; mi++)
            #pragma unroll
            for (int ni = 0; ni < 4; ni++)
                acc[mi][ni] = mfma16(fa[mi], fb[ni], acc[mi][ni]);
        // tile t+1 ready; tile t+2's 4 loads stay in flight across the barrier
        asm volatile("s_waitcnt vmcnt(4) lgkmcnt(0)" ::: "memory");
        __builtin_amdgcn_s_barrier();
        __builtin_amdgcn_sched_barrier(0);
        cur = (cur == 2) ? 0 : cur + 1;
    }
    // t = 14: no stage; drain remaining tile-15 loads at the barrier
    {
        bf16x8 fa[4], fb[4];
        #pragma unroll
        for (int mi = 0; mi < 4; mi++)
            fa[mi] = ldsfrag(&AsF[cur][(wm + mi * 16 + col) * 32 + rdo]);
        #pragma unroll
        for (int ni = 0; ni < 4; ni++)
            fb[ni] = ldsfrag(&BsF[cur][(wn + ni * 16 + col) * 32 + rdo]);
        #pragma unroll
        for (int mi = 0; mi < 4; mi++)
            #pragma unroll
            for (int ni = 0; ni < 4; ni++)
                acc[mi][ni] = mfma16(fa[mi], fb[ni], acc[mi][ni]);
        asm volatile("s_waitcnt vmcnt(0) lgkmcnt(0)" ::: "memory");
        __builtin_amdgcn_s_barrier();
        __builtin_amdgcn_sched_barrier(0);
        cur = (cur == 2) ? 0 : cur + 1;
    }
    // t = 15: last tile, no trailing barrier
    {
        bf16x8 fa[4], fb[4];
        #pragma unroll
        for (int mi = 0; mi < 4; mi++)
            fa[mi] = ldsfrag(&AsF[cur][(wm + mi * 16 + col) * 32 + rdo]);
        #pragma unroll
        for (int ni = 0; ni < 4; ni++)
            fb[ni] = ldsfrag(&BsF[cur][(wn + ni * 16 + col) * 32 + rdo]);
        #pragma unroll
        for (int mi = 0; mi < 4; mi++)
            #pragma unroll
            for (int ni = 0; ni < 4; ni++)
                acc[mi][ni] = mfma16(fa[mi], fb[ni], acc[mi][ni]);
    }

    if (mode == 0) {
        #pragma unroll
        for (int ni = 0; ni < 4; ni++) {
            const int gn = n0 + wn + ni * 16 + col;     // 0..1535
            const float bv = b2f(bias[gn]);
            const int seg = gn >> 9;
            #pragma unroll
            for (int mi = 0; mi < 4; mi++) {
                const int gmb = m0 + wm + mi * 16 + quad * 4;
                if (seg < 2) {
                    u16* dst = (seg == 0) ? (u16*)out0 : out1;
                    #pragma unroll
                    for (int r = 0; r < 4; r++)
                        dst[(size_t)(gmb + r) * 512 + (gn & 511)] = f2b(acc[mi][ni][r] + bv);
                } else {
                    const int d = gn & 63, hh = (gn >> 6) & 7;
                    const int bb = gmb >> 13, t = gmb & 8191;
                    u16 pb[4];
                    #pragma unroll
                    for (int r = 0; r < 4; r++) pb[r] = f2b(acc[mi][ni][r] + bv);
                    uint2 pk;
                    pk.x = pb[0] | ((u32)pb[1] << 16);
                    pk.y = pb[2] | ((u32)pb[3] << 16);
                    *(uint2*)&out2[((size_t)(bb * 8 + hh) * 64 + d) * 8192 + t] = pk;
                }
            }
        }
    } else {
        const int outf32 = *flagp;
        #pragma unroll
        for (int ni = 0; ni < 4; ni++) {
            const int gn = n0 + wn + ni * 16 + col;
            const float bv = b2f(bias[gn]);
            #pragma unroll
            for (int mi = 0; mi < 4; mi++) {
                #pragma unroll
                for (int r = 0; r < 4; r++) {
                    const int gm = m0 + wm + mi * 16 + quad * 4 + r;
                    const float v = acc[mi][ni][r] + bv;
                    if (outf32) ((float*)out0)[(size_t)gm * 512 + gn] = v;
                    else        ((u16*)out0)[(size_t)gm * 512 + gn]  = f2b(v);
                }
            }
        }
    }
}

// Local attention, block = (b,h,chunk): 256 queries, 8 waves x 32 queries
// (512 threads). Round-4 post-mortem: 2 waves/SIMD couldn't hide the
// ds->MFMA->exp->ds->MFMA chain (MfmaUtil 19%, all pipes idle). Halving
// per-wave state lets __launch_bounds__(512,4) hold 4 waves/SIMD ->
// 16 waves/CU at the same LDS footprint.
// Double-buffered 64-key sub-chunks over [c-1,c,c+1]; contiguous valid range,
// one barrier per iteration, prefetch in flight across compute.
// No max-subtraction (scores O(6), softmax shift-invariant).
// S^T = K.Q^T so P packs to LDS as b64; O^T = VT.P so normalization is
// per-lane and stores pack as 8B. V input is pre-transposed [b,h,d][t].
#define PSW 72
__global__ __launch_bounds__(512, 4)
void attn_local(const u16* __restrict__ Qg, const u16* __restrict__ Kg,
                const u16* __restrict__ VTg, u16* __restrict__ Og)
{
    __shared__ __align__(16) u16 Ks[2][64 * 64];   // 16 KB
    __shared__ __align__(16) u16 VTs[2][64 * 64];  // 16 KB
    __shared__ __align__(16) u16 Ps[8][32 * PSW];  // 36 KB (wave-private)

    const int tid  = threadIdx.x;
    const int lane = tid & 63;
    const int wv   = tid >> 6;          // 0..7
    const int col  = lane & 15;
    const int quad = lane >> 4;

    const int idx = blockIdx.x;
    const int c = idx & 31;
    const int h = (idx >> 5) & 7;
    const int b = idx >> 8;

    const int t0 = c * WW;
    const int wq = wv * 32;             // this wave's 32 queries

    const int sc_lo = (c == 0) ? 4 : 0;                 // kstart >= 0
    const int nsc   = (c == 0 || c == 31) ? 8 : 12;     // kstart < T

    const int ldr = lane >> 3;            // staging row-within-group (0..7)
    const int ldc = lane & 7;

    // Q fragments (B-operand): lane holds Q[t0+wq+qi*16+col][kk*32+quad*8..+8]
    bf16x8 qf[2][2];
    {
        const size_t qbase = ((size_t)(b * TT + t0 + wq + col)) * DD + h * DH + quad * 8;
        #pragma unroll
        for (int qi = 0; qi < 2; qi++)
            #pragma unroll
            for (int kk = 0; kk < 2; kk++)
                qf[qi][kk] = *(const bf16x8*)(Qg + qbase + (size_t)qi * 16 * DD + kk * 32);
    }

    f32x4 o[4][2] = {};                 // O^T accum: [di(d-tile)][qi(q-tile)]
    float lsum[2] = {0.f, 0.f};         // per-lane partial l for q=qi*16+col

    u16* psb = &Ps[wv][0];

    // prefetch first sub-chunk into buf 0 (one K + one VT row-group per wave)
    {
        const int kstart = t0 - WW + sc_lo * 64;
        const int rr = wv * 8 + ldr;
        const int cb = ldc ^ (rr & 7);
        gl_lds(Kg  + ((size_t)(b * TT + kstart + rr)) * DD + h * DH + cb * 8,
               &Ks[0][wv * 512]);
        gl_lds(VTg + ((size_t)((b * HH + h) * DH + rr)) * TT + kstart + cb * 8,
               &VTs[0][wv * 512]);
    }

    for (int it = 0; it < nsc; it++) {
        __syncthreads();   // drains loads for buf it&1; prev readers of other buf done
        if (it + 1 < nsc) {
            const int kstart = t0 - WW + (sc_lo + it + 1) * 64;
            const int buf = (it + 1) & 1;
            const int rr = wv * 8 + ldr;
            const int cb = ldc ^ (rr & 7);
            gl_lds(Kg  + ((size_t)(b * TT + kstart + rr)) * DD + h * DH + cb * 8,
                   &Ks[buf][wv * 512]);
            gl_lds(VTg + ((size_t)((b * HH + h) * DH + rr)) * TT + kstart + cb * 8,
                   &VTs[buf][wv * 512]);
        }
        const u16* ks = &Ks[it & 1][0];
        const u16* vs = &VTs[it & 1][0];

        // S^T[key][q] : A = K rows, B = Q rows (32 queries per wave)
        f32x4 s[4][2];
        #pragma unroll
        for (int ns = 0; ns < 4; ns++)
            #pragma unroll
            for (int qi = 0; qi < 2; qi++)
                s[ns][qi] = (f32x4){0.f, 0.f, 0.f, 0.f};
        #pragma unroll
        for (int ns = 0; ns < 4; ns++) {
            const int row = ns * 16 + col;
            bf16x8 ka0 = ldsfrag(&ks[row * 64 + ((0 + quad) ^ (col & 7)) * 8]);
            bf16x8 ka1 = ldsfrag(&ks[row * 64 + ((4 + quad) ^ (col & 7)) * 8]);
            #pragma unroll
            for (int qi = 0; qi < 2; qi++) {
                s[ns][qi] = mfma16(ka0, qf[qi][0], s[ns][qi]);
                s[ns][qi] = mfma16(ka1, qf[qi][1], s[ns][qi]);
            }
        }

        // p = exp(s/8), accumulate l (fp32, pre-rounding), pack -> b64 write
        #pragma unroll
        for (int ns = 0; ns < 4; ns++) {
            #pragma unroll
            for (int qi = 0; qi < 2; qi++) {
                u16 pb[4];
                #pragma unroll
                for (int r = 0; r < 4; r++) {
                    const float p = __expf(s[ns][qi][r] * 0.125f);
                    pb[r] = f2b(p);
                    lsum[qi] += p;
                }
                uint2 pk;
                pk.x = pb[0] | ((u32)pb[1] << 16);
                pk.y = pb[2] | ((u32)pb[3] << 16);
                *(uint2*)&psb[(qi * 16 + col) * PSW + ns * 16 + quad * 4] = pk;
            }
        }
        asm volatile("" ::: "memory");   // order Ps write -> read (wave-private)

        // O^T += VT . P : A = VT (m=d), B = Ps rows (n=q)
        #pragma unroll
        for (int kt = 0; kt < 2; kt++) {
            bf16x8 pf[2];
            #pragma unroll
            for (int qi = 0; qi < 2; qi++)
                pf[qi] = ldsfrag(&psb[(qi * 16 + col) * PSW + kt * 32 + quad * 8]);
            #pragma unroll
            for (int di = 0; di < 4; di++) {
                bf16x8 va = ldsfrag(&vs[(di * 16 + col) * 64 + ((kt * 4 + quad) ^ (col & 7)) * 8]);
                #pragma unroll
                for (int qi = 0; qi < 2; qi++)
                    o[di][qi] = mfma16(va, pf[qi], o[di][qi]);
            }
        }
    }

    // final l reduction over quads (lanes col,col+16,col+32,col+48 share q)
    #pragma unroll
    for (int qi = 0; qi < 2; qi++) {
        float l = lsum[qi];
        l += __shfl_xor(l, 16);
        l += __shfl_xor(l, 32);
        lsum[qi] = 1.0f / l;
    }

    // store O^T: element (di,qi,r): d = di*16+quad*4+r, q = qi*16+col
    #pragma unroll
    for (int qi = 0; qi < 2; qi++) {
        const size_t ob = ((size_t)(b * TT + t0 + wq + qi * 16 + col)) * DD + h * DH + quad * 4;
        #pragma unroll
        for (int di = 0; di < 4; di++) {
            u16 pb[4];
            #pragma unroll
            for (int r = 0; r < 4; r++) pb[r] = f2b(o[di][qi][r] * lsum[qi]);
            uint2 pk;
            pk.x = pb[0] | ((u32)pb[1] << 16);
            pk.y = pb[2] | ((u32)pb[3] << 16);
            *(uint2*)&Og[ob + di * 16] = pk;
        }
    }
}

extern "C" void kernel_launch(void* const* d_in, const int* in_sizes, int n_in,
                              void* d_out, int out_size, void* d_ws, size_t ws_size,
                              hipStream_t stream)
{
    u16* ws   = (u16*)d_ws;
    u16* xb   = ws;                       // NX
    u16* Wcat = xb + NX;                  // 3*NW  (Wq,Wk,Wv rows concatenated)
    u16* Wob  = Wcat + 3 * NW;            // NW
    u16* bcat = Wob + NW;                 // 1536
    u16* bob  = bcat + 1536;              // 512
    u16* qws  = bob + 512;                // NX   Q  [b*T+t][h*64+d]
    u16* kws  = qws + NX;                 // NX   K  same
    u16* vtws = kws + NX;                 // NX   V^T [(b*8+h)*64+d][t]
    u16* aws  = vtws + NX;                // NX   attn out [b*T+t][h*64+d]
    int* flag = (int*)(aws + NX);

    // 9439232 elements / 8 per thread / 256 per block = 4609 blocks
    convert_all<<<4609, 256, 0, stream>>>(
        d_in[0], d_in[1], d_in[2], d_in[3], d_in[4], d_in[5], d_in[6], d_in[7], d_in[8],
        xb, Wcat, Wob, bcat, bob, flag);

    // fused QKV projection: N = 1536
    gemm128<<<dim3(128, 12), 256, 0, stream>>>(xb, Wcat, bcat, qws, kws, vtws, 0, flag);
    // local attention: 512 blocks x 512 threads
    attn_local<<<dim3(BB * HH * 32), 512, 0, stream>>>(qws, kws, vtws, aws);
    // output projection
    gemm128<<<dim3(128, 4), 256, 0, stream>>>(aws, Wob, bob, d_out, nullptr, nullptr, 1, flag);
}

// Round 6
// 200.866 us; speedup vs baseline: 1.0190x; 1.0190x over previous
//
#include <hip/hip_runtime.h>
#include <hip/hip_bf16.h>

typedef unsigned short u16;
typedef unsigned int   u32;
typedef __bf16 bf16x8 __attribute__((ext_vector_type(8)));
typedef float  f32x4  __attribute__((ext_vector_type(4)));

#define BB 2
#define TT 8192
#define DD 512
#define HH 8
#define WW 256
#define DH 64
#define NX 8388608   // 16384*512
#define NW 262144    // 512*512

__device__ __forceinline__ float b2f(u16 u) {
    unsigned int x = ((unsigned int)u) << 16;
    return __builtin_bit_cast(float, x);
}
__device__ __forceinline__ u16 f2b(float f) {
    __bf16 h = (__bf16)f;
    return __builtin_bit_cast(u16, h);
}
__device__ __forceinline__ bf16x8 ldsfrag(const u16* p) {
    return *(const bf16x8*)p;
}
__device__ __forceinline__ f32x4 mfma16(bf16x8 a, bf16x8 b, f32x4 c) {
    return __builtin_amdgcn_mfma_f32_16x16x32_bf16(a, b, c, 0, 0, 0);
}

typedef __attribute__((address_space(1))) u32 gu32;
typedef __attribute__((address_space(3))) u32 lu32;
// async global->LDS, 16B per lane, dest = wave-uniform base + lane*16
__device__ __forceinline__ void gl_lds(const u16* g, u16* l) {
    __builtin_amdgcn_global_load_lds((gu32*)g, (lu32*)l, 16, 0, 0);
}

// ---- convert all 9 inputs to bf16 in workspace (vectorized, 8 elem/thread).
// dtype flag computed per-block from x's first 2048 u16 (deterministic);
// block 0 persists it for the O-proj epilogue.
__device__ __forceinline__ void cvt8(const void* s, u16* d, long i, int f) {
    if (f) {
        const u32* sp = (const u32*)s + i;
        uint4 a = *(const uint4*)(sp);
        uint4 b = *(const uint4*)(sp + 4);
        u16 o[8];
        o[0] = f2b(__builtin_bit_cast(float, a.x));
        o[1] = f2b(__builtin_bit_cast(float, a.y));
        o[2] = f2b(__builtin_bit_cast(float, a.z));
        o[3] = f2b(__builtin_bit_cast(float, a.w));
        o[4] = f2b(__builtin_bit_cast(float, b.x));
        o[5] = f2b(__builtin_bit_cast(float, b.y));
        o[6] = f2b(__builtin_bit_cast(float, b.z));
        o[7] = f2b(__builtin_bit_cast(float, b.w));
        *(uint4*)(d + i) = *(const uint4*)o;
    } else {
        *(uint4*)(d + i) = *(const uint4*)((const u16*)s + i);
    }
}

__global__ void convert_all(const void* x, const void* Wq, const void* bq,
                            const void* Wk, const void* bk, const void* Wv,
                            const void* bv, const void* Wo, const void* bo,
                            u16* __restrict__ xb, u16* __restrict__ Wcat,
                            u16* __restrict__ Wob, u16* __restrict__ bcat,
                            u16* __restrict__ bob, int* __restrict__ flagw)
{
    __shared__ int sflag;
    const int tid = threadIdx.x;
    if (tid == 0) sflag = 0;
    __syncthreads();
    int mybad = 0;
    for (int i = tid; i < 2048; i += 256) {
        float v = b2f(((const u16*)x)[i]);
        if (!(fabsf(v) < 100.f)) mybad = 1;   // fp32 mantissa halves look wild
    }
    if (mybad) atomicOr(&sflag, 1);
    __syncthreads();
    const int f = sflag ? 1 : 0;
    if (blockIdx.x == 0 && tid == 0) *flagw = f;

    long i = ((long)blockIdx.x * 256 + tid) * 8;
    if (i < NX)            { cvt8(x,  xb,           i, f); return; }
    i -= NX;
    if (i < NW)            { cvt8(Wq, Wcat,         i, f); return; }
    i -= NW;
    if (i < NW)            { cvt8(Wk, Wcat + NW,    i, f); return; }
    i -= NW;
    if (i < NW)            { cvt8(Wv, Wcat + 2*NW,  i, f); return; }
    i -= NW;
    if (i < NW)            { cvt8(Wo, Wob,          i, f); return; }
    i -= NW;
    if (i < 512)           { cvt8(bq, bcat,         i, f); return; }
    i -= 512;
    if (i < 512)           { cvt8(bk, bcat + 512,   i, f); return; }
    i -= 512;
    if (i < 512)           { cvt8(bv, bcat + 1024,  i, f); return; }
    i -= 512;
    if (i < 512)           { cvt8(bo, bob,          i, f); }
}

// 128x128-tile GEMM, K=512. Round-7: STATIC-index 3-buffer ring (T3+T4).
// Round-6 post-mortem: counted-vmcnt ring with RUNTIME buffer index `cur`
// gave zero gain - compiler cannot disambiguate gl_lds dest vs ds_read src
// with dynamic LDS indices and conservatively serializes (the verified
// 8-phase template m201 works precisely because buffer indices are static).
// Fix: fully unroll the 16 K-steps (#pragma unroll; t%3 folds to constants)
// so every LDS address is compile-time; keep vmcnt(4) - tile t+1 ready,
// tile t+2's 4 loads stay in flight across the barrier (never drain to 0
// mid-loop). Also fix round-6's 3.1M bank conflicts: swizzle slot with
// ((row>>1)&3) so each in-order 8-lane group covers 8 distinct bank quads
// (read side: quad ^ ((col>>1)&3), uniform over mi since wm,mi*16 = 0 mod 4
// after >>1).
// out[m,n] = sum_k A[m,k]*Bw[n,k] + bias[n].
// mode 0 (fused QKV, N=1536): seg0->out0 (Q [t][h*64+d]), seg1->out1 (K same),
//   seg2->out2 (V TRANSPOSED: [(b*8+h)*64+d][t]).
// mode 1 (O-proj): out0, fp32 if *flagp else bf16.
__global__ __launch_bounds__(256, 3)
void gemm128(const u16* __restrict__ A, const u16* __restrict__ Bw,
             const u16* __restrict__ bias, void* __restrict__ out0,
             u16* __restrict__ out1, u16* __restrict__ out2,
             int mode, const int* __restrict__ flagp)
{
    __shared__ __align__(16) u16 AsF[3][128 * 32];   // 3 x 8 KB
    __shared__ __align__(16) u16 BsF[3][128 * 32];   // 3 x 8 KB (48 KB total)

    const int tid  = threadIdx.x;
    const int lane = tid & 63;
    const int wv   = tid >> 6;
    const int col  = lane & 15;
    const int quad = lane >> 4;
    const int wm   = (wv & 1) * 64;
    const int wn   = (wv >> 1) * 64;
    const int m0   = blockIdx.x * 128;
    const int n0   = blockIdx.y * 128;

    f32x4 acc[4][4] = {};

    // staging: per wave 2 gl_lds for A + 2 for B (1KB each, 16 rows x 64B).
    // lane l -> row group*16 + (l>>2), 16B slot l&3; source slot
    // XOR-swizzled by ((row>>1)&3) -> banks spread across all 32.
    const int srow = lane >> 2;
    const int scol = lane & 3;

    auto STAGE = [&](int buf, int k0) {
        #pragma unroll
        for (int i = 0; i < 2; i++) {
            const int r  = wv * 32 + i * 16 + srow;
            const int cb = scol ^ ((r >> 1) & 3);
            gl_lds(A  + (size_t)(m0 + r) * 512 + k0 + cb * 8, &AsF[buf][(wv * 2 + i) * 512]);
            gl_lds(Bw + (size_t)(n0 + r) * 512 + k0 + cb * 8, &BsF[buf][(wv * 2 + i) * 512]);
        }
    };

    // read slot: row = wm+mi*16+col -> ((row>>1)&3) == ((col>>1)&3)
    const int rdo = (quad ^ ((col >> 1) & 3)) * 8;

    // prologue: tiles 0,1 in flight; wait for tile 0 only (4 loads stay out)
    STAGE(0, 0);
    STAGE(1, 32);
    asm volatile("s_waitcnt vmcnt(4) lgkmcnt(0)" ::: "memory");
    __builtin_amdgcn_s_barrier();
    __builtin_amdgcn_sched_barrier(0);

    #pragma unroll
    for (int t = 0; t < 16; ++t) {
        if (t < 14) STAGE((t + 2) % 3, (t + 2) * 32);   // static after unroll
        const u16* as = &AsF[t % 3][0];
        const u16* bs = &BsF[t % 3][0];
        bf16x8 fa[4], fb[4];
        #pragma unroll
        for (int mi = 0; mi < 4; mi++)
            fa[mi] = ldsfrag(&as[(wm + mi * 16 + col) * 32 + rdo]);
        #pragma unroll
        for (int ni = 0; ni < 4; ni++)
            fb[ni] = ldsfrag(&bs[(wn + ni * 16 + col) * 32 + rdo]);
        #pragma unroll
        for (int mi = 0; mi < 4; mi++)
            #pragma unroll
            for (int ni = 0; ni < 4; ni++)
                acc[mi][ni] = mfma16(fa[mi], fb[ni], acc[mi][ni]);
        if (t < 14) {
            // tile t+1 ready; tile t+2's 4 loads stay in flight across barrier
            asm volatile("s_waitcnt vmcnt(4) lgkmcnt(0)" ::: "memory");
            __builtin_amdgcn_s_barrier();
            __builtin_amdgcn_sched_barrier(0);
        } else if (t == 14) {
            asm volatile("s_waitcnt vmcnt(0) lgkmcnt(0)" ::: "memory");
            __builtin_amdgcn_s_barrier();
            __builtin_amdgcn_sched_barrier(0);
        }
    }

    if (mode == 0) {
        #pragma unroll
        for (int ni = 0; ni < 4; ni++) {
            const int gn = n0 + wn + ni * 16 + col;     // 0..1535
            const float bv = b2f(bias[gn]);
            const int seg = gn >> 9;
            #pragma unroll
            for (int mi = 0; mi < 4; mi++) {
                const int gmb = m0 + wm + mi * 16 + quad * 4;
                if (seg < 2) {
                    u16* dst = (seg == 0) ? (u16*)out0 : out1;
                    #pragma unroll
                    for (int r = 0; r < 4; r++)
                        dst[(size_t)(gmb + r) * 512 + (gn & 511)] = f2b(acc[mi][ni][r] + bv);
                } else {
                    const int d = gn & 63, hh = (gn >> 6) & 7;
                    const int bb = gmb >> 13, t = gmb & 8191;
                    u16 pb[4];
                    #pragma unroll
                    for (int r = 0; r < 4; r++) pb[r] = f2b(acc[mi][ni][r] + bv);
                    uint2 pk;
                    pk.x = pb[0] | ((u32)pb[1] << 16);
                    pk.y = pb[2] | ((u32)pb[3] << 16);
                    *(uint2*)&out2[((size_t)(bb * 8 + hh) * 64 + d) * 8192 + t] = pk;
                }
            }
        }
    } else {
        const int outf32 = *flagp;
        #pragma unroll
        for (int ni = 0; ni < 4; ni++) {
            const int gn = n0 + wn + ni * 16 + col;
            const float bv = b2f(bias[gn]);
            #pragma unroll
            for (int mi = 0; mi < 4; mi++) {
                #pragma unroll
                for (int r = 0; r < 4; r++) {
                    const int gm = m0 + wm + mi * 16 + quad * 4 + r;
                    const float v = acc[mi][ni][r] + bv;
                    if (outf32) ((float*)out0)[(size_t)gm * 512 + gn] = v;
                    else        ((u16*)out0)[(size_t)gm * 512 + gn]  = f2b(v);
                }
            }
        }
    }
}

// Local attention, block = (b,h,chunk): 256 queries, 8 waves x 32 queries
// (512 threads). Round-4 post-mortem: 2 waves/SIMD couldn't hide the
// ds->MFMA->exp->ds->MFMA chain (MfmaUtil 19%, all pipes idle). Halving
// per-wave state lets __launch_bounds__(512,4) hold 4 waves/SIMD ->
// 16 waves/CU at the same LDS footprint.
// Double-buffered 64-key sub-chunks over [c-1,c,c+1]; contiguous valid range,
// one barrier per iteration, prefetch in flight across compute.
// No max-subtraction (scores O(6), softmax shift-invariant).
// S^T = K.Q^T so P packs to LDS as b64; O^T = VT.P so normalization is
// per-lane and stores pack as 8B. V input is pre-transposed [b,h,d][t].
#define PSW 72
__global__ __launch_bounds__(512, 4)
void attn_local(const u16* __restrict__ Qg, const u16* __restrict__ Kg,
                const u16* __restrict__ VTg, u16* __restrict__ Og)
{
    __shared__ __align__(16) u16 Ks[2][64 * 64];   // 16 KB
    __shared__ __align__(16) u16 VTs[2][64 * 64];  // 16 KB
    __shared__ __align__(16) u16 Ps[8][32 * PSW];  // 36 KB (wave-private)

    const int tid  = threadIdx.x;
    const int lane = tid & 63;
    const int wv   = tid >> 6;          // 0..7
    const int col  = lane & 15;
    const int quad = lane >> 4;

    const int idx = blockIdx.x;
    const int c = idx & 31;
    const int h = (idx >> 5) & 7;
    const int b = idx >> 8;

    const int t0 = c * WW;
    const int wq = wv * 32;             // this wave's 32 queries

    const int sc_lo = (c == 0) ? 4 : 0;                 // kstart >= 0
    const int nsc   = (c == 0 || c == 31) ? 8 : 12;     // kstart < T

    const int ldr = lane >> 3;            // staging row-within-group (0..7)
    const int ldc = lane & 7;

    // Q fragments (B-operand): lane holds Q[t0+wq+qi*16+col][kk*32+quad*8..+8]
    bf16x8 qf[2][2];
    {
        const size_t qbase = ((size_t)(b * TT + t0 + wq + col)) * DD + h * DH + quad * 8;
        #pragma unroll
        for (int qi = 0; qi < 2; qi++)
            #pragma unroll
            for (int kk = 0; kk < 2; kk++)
                qf[qi][kk] = *(const bf16x8*)(Qg + qbase + (size_t)qi * 16 * DD + kk * 32);
    }

    f32x4 o[4][2] = {};                 // O^T accum: [di(d-tile)][qi(q-tile)]
    float lsum[2] = {0.f, 0.f};         // per-lane partial l for q=qi*16+col

    u16* psb = &Ps[wv][0];

    // prefetch first sub-chunk into buf 0 (one K + one VT row-group per wave)
    {
        const int kstart = t0 - WW + sc_lo * 64;
        const int rr = wv * 8 + ldr;
        const int cb = ldc ^ (rr & 7);
        gl_lds(Kg  + ((size_t)(b * TT + kstart + rr)) * DD + h * DH + cb * 8,
               &Ks[0][wv * 512]);
        gl_lds(VTg + ((size_t)((b * HH + h) * DH + rr)) * TT + kstart + cb * 8,
               &VTs[0][wv * 512]);
    }

    for (int it = 0; it < nsc; it++) {
        __syncthreads();   // drains loads for buf it&1; prev readers of other buf done
        if (it + 1 < nsc) {
            const int kstart = t0 - WW + (sc_lo + it + 1) * 64;
            const int buf = (it + 1) & 1;
            const int rr = wv * 8 + ldr;
            const int cb = ldc ^ (rr & 7);
            gl_lds(Kg  + ((size_t)(b * TT + kstart + rr)) * DD + h * DH + cb * 8,
                   &Ks[buf][wv * 512]);
            gl_lds(VTg + ((size_t)((b * HH + h) * DH + rr)) * TT + kstart + cb * 8,
                   &VTs[buf][wv * 512]);
        }
        const u16* ks = &Ks[it & 1][0];
        const u16* vs = &VTs[it & 1][0];

        // S^T[key][q] : A = K rows, B = Q rows (32 queries per wave)
        f32x4 s[4][2];
        #pragma unroll
        for (int ns = 0; ns < 4; ns++)
            #pragma unroll
            for (int qi = 0; qi < 2; qi++)
                s[ns][qi] = (f32x4){0.f, 0.f, 0.f, 0.f};
        #pragma unroll
        for (int ns = 0; ns < 4; ns++) {
            const int row = ns * 16 + col;
            bf16x8 ka0 = ldsfrag(&ks[row * 64 + ((0 + quad) ^ (col & 7)) * 8]);
            bf16x8 ka1 = ldsfrag(&ks[row * 64 + ((4 + quad) ^ (col & 7)) * 8]);
            #pragma unroll
            for (int qi = 0; qi < 2; qi++) {
                s[ns][qi] = mfma16(ka0, qf[qi][0], s[ns][qi]);
                s[ns][qi] = mfma16(ka1, qf[qi][1], s[ns][qi]);
            }
        }

        // p = exp(s/8), accumulate l (fp32, pre-rounding), pack -> b64 write
        #pragma unroll
        for (int ns = 0; ns < 4; ns++) {
            #pragma unroll
            for (int qi = 0; qi < 2; qi++) {
                u16 pb[4];
                #pragma unroll
                for (int r = 0; r < 4; r++) {
                    const float p = __expf(s[ns][qi][r] * 0.125f);
                    pb[r] = f2b(p);
                    lsum[qi] += p;
                }
                uint2 pk;
                pk.x = pb[0] | ((u32)pb[1] << 16);
                pk.y = pb[2] | ((u32)pb[3] << 16);
                *(uint2*)&psb[(qi * 16 + col) * PSW + ns * 16 + quad * 4] = pk;
            }
        }
        asm volatile("" ::: "memory");   // order Ps write -> read (wave-private)

        // O^T += VT . P : A = VT (m=d), B = Ps rows (n=q)
        #pragma unroll
        for (int kt = 0; kt < 2; kt++) {
            bf16x8 pf[2];
            #pragma unroll
            for (int qi = 0; qi < 2; qi++)
                pf[qi] = ldsfrag(&psb[(qi * 16 + col) * PSW + kt * 32 + quad * 8]);
            #pragma unroll
            for (int di = 0; di < 4; di++) {
                bf16x8 va = ldsfrag(&vs[(di * 16 + col) * 64 + ((kt * 4 + quad) ^ (col & 7)) * 8]);
                #pragma unroll
                for (int qi = 0; qi < 2; qi++)
                    o[di][qi] = mfma16(va, pf[qi], o[di][qi]);
            }
        }
    }

    // final l reduction over quads (lanes col,col+16,col+32,col+48 share q)
    #pragma unroll
    for (int qi = 0; qi < 2; qi++) {
        float l = lsum[qi];
        l += __shfl_xor(l, 16);
        l += __shfl_xor(l, 32);
        lsum[qi] = 1.0f / l;
    }

    // store O^T: element (di,qi,r): d = di*16+quad*4+r, q = qi*16+col
    #pragma unroll
    for (int qi = 0; qi < 2; qi++) {
        const size_t ob = ((size_t)(b * TT + t0 + wq + qi * 16 + col)) * DD + h * DH + quad * 4;
        #pragma unroll
        for (int di = 0; di < 4; di++) {
            u16 pb[4];
            #pragma unroll
            for (int r = 0; r < 4; r++) pb[r] = f2b(o[di][qi][r] * lsum[qi]);
            uint2 pk;
            pk.x = pb[0] | ((u32)pb[1] << 16);
            pk.y = pb[2] | ((u32)pb[3] << 16);
            *(uint2*)&Og[ob + di * 16] = pk;
        }
    }
}

extern "C" void kernel_launch(void* const* d_in, const int* in_sizes, int n_in,
                              void* d_out, int out_size, void* d_ws, size_t ws_size,
                              hipStream_t stream)
{
    u16* ws   = (u16*)d_ws;
    u16* xb   = ws;                       // NX
    u16* Wcat = xb + NX;                  // 3*NW  (Wq,Wk,Wv rows concatenated)
    u16* Wob  = Wcat + 3 * NW;            // NW
    u16* bcat = Wob + NW;                 // 1536
    u16* bob  = bcat + 1536;              // 512
    u16* qws  = bob + 512;                // NX   Q  [b*T+t][h*64+d]
    u16* kws  = qws + NX;                 // NX   K  same
    u16* vtws = kws + NX;                 // NX   V^T [(b*8+h)*64+d][t]
    u16* aws  = vtws + NX;                // NX   attn out [b*T+t][h*64+d]
    int* flag = (int*)(aws + NX);

    // 9439232 elements / 8 per thread / 256 per block = 4609 blocks
    convert_all<<<4609, 256, 0, stream>>>(
        d_in[0], d_in[1], d_in[2], d_in[3], d_in[4], d_in[5], d_in[6], d_in[7], d_in[8],
        xb, Wcat, Wob, bcat, bob, flag);

    // fused QKV projection: N = 1536
    gemm128<<<dim3(128, 12), 256, 0, stream>>>(xb, Wcat, bcat, qws, kws, vtws, 0, flag);
    // local attention: 512 blocks x 512 threads
    attn_local<<<dim3(BB * HH * 32), 512, 0, stream>>>(qws, kws, vtws, aws);
    // output projection
    gemm128<<<dim3(128, 4), 256, 0, stream>>>(aws, Wob, bob, d_out, nullptr, nullptr, 1, flag);
}

// Round 7
// 193.032 us; speedup vs baseline: 1.0604x; 1.0406x over previous
//
#include <hip/hip_runtime.h>
#include <hip/hip_bf16.h>

typedef unsigned short u16;
typedef unsigned int   u32;
typedef __bf16 bf16x8 __attribute__((ext_vector_type(8)));
typedef float  f32x4  __attribute__((ext_vector_type(4)));

#define BB 2
#define TT 8192
#define DD 512
#define HH 8
#define WW 256
#define DH 64
#define NX 8388608   // 16384*512
#define NW 262144    // 512*512

__device__ __forceinline__ float b2f(u16 u) {
    unsigned int x = ((unsigned int)u) << 16;
    return __builtin_bit_cast(float, x);
}
__device__ __forceinline__ u16 f2b(float f) {
    __bf16 h = (__bf16)f;
    return __builtin_bit_cast(u16, h);
}
__device__ __forceinline__ bf16x8 ldsfrag(const u16* p) {
    return *(const bf16x8*)p;
}
__device__ __forceinline__ f32x4 mfma16(bf16x8 a, bf16x8 b, f32x4 c) {
    return __builtin_amdgcn_mfma_f32_16x16x32_bf16(a, b, c, 0, 0, 0);
}

typedef __attribute__((address_space(1))) u32 gu32;
typedef __attribute__((address_space(3))) u32 lu32;
// async global->LDS, 16B per lane, dest = wave-uniform base + lane*16
__device__ __forceinline__ void gl_lds(const u16* g, u16* l) {
    __builtin_amdgcn_global_load_lds((gu32*)g, (lu32*)l, 16, 0, 0);
}

// ---- convert all 9 inputs to bf16 in workspace (vectorized, 8 elem/thread).
__device__ __forceinline__ void cvt8(const void* s, u16* d, long i, int f) {
    if (f) {
        const u32* sp = (const u32*)s + i;
        uint4 a = *(const uint4*)(sp);
        uint4 b = *(const uint4*)(sp + 4);
        u16 o[8];
        o[0] = f2b(__builtin_bit_cast(float, a.x));
        o[1] = f2b(__builtin_bit_cast(float, a.y));
        o[2] = f2b(__builtin_bit_cast(float, a.z));
        o[3] = f2b(__builtin_bit_cast(float, a.w));
        o[4] = f2b(__builtin_bit_cast(float, b.x));
        o[5] = f2b(__builtin_bit_cast(float, b.y));
        o[6] = f2b(__builtin_bit_cast(float, b.z));
        o[7] = f2b(__builtin_bit_cast(float, b.w));
        *(uint4*)(d + i) = *(const uint4*)o;
    } else {
        *(uint4*)(d + i) = *(const uint4*)((const u16*)s + i);
    }
}

__global__ void convert_all(const void* x, const void* Wq, const void* bq,
                            const void* Wk, const void* bk, const void* Wv,
                            const void* bv, const void* Wo, const void* bo,
                            u16* __restrict__ xb, u16* __restrict__ Wcat,
                            u16* __restrict__ Wob, u16* __restrict__ bcat,
                            u16* __restrict__ bob, int* __restrict__ flagw)
{
    __shared__ int sflag;
    const int tid = threadIdx.x;
    if (tid == 0) sflag = 0;
    __syncthreads();
    int mybad = 0;
    for (int i = tid; i < 2048; i += 256) {
        float v = b2f(((const u16*)x)[i]);
        if (!(fabsf(v) < 100.f)) mybad = 1;   // fp32 mantissa halves look wild
    }
    if (mybad) atomicOr(&sflag, 1);
    __syncthreads();
    const int f = sflag ? 1 : 0;
    if (blockIdx.x == 0 && tid == 0) *flagw = f;

    long i = ((long)blockIdx.x * 256 + tid) * 8;
    if (i < NX)            { cvt8(x,  xb,           i, f); return; }
    i -= NX;
    if (i < NW)            { cvt8(Wq, Wcat,         i, f); return; }
    i -= NW;
    if (i < NW)            { cvt8(Wk, Wcat + NW,    i, f); return; }
    i -= NW;
    if (i < NW)            { cvt8(Wv, Wcat + 2*NW,  i, f); return; }
    i -= NW;
    if (i < NW)            { cvt8(Wo, Wob,          i, f); return; }
    i -= NW;
    if (i < 512)           { cvt8(bq, bcat,         i, f); return; }
    i -= 512;
    if (i < 512)           { cvt8(bk, bcat + 512,   i, f); return; }
    i -= 512;
    if (i < 512)           { cvt8(bv, bcat + 1024,  i, f); return; }
    i -= 512;
    if (i < 512)           { cvt8(bo, bob,          i, f); }
}

// 256x128-tile GEMM, K=512. Round-8: 8-phase-class structure (m201 port).
// Rounds 4-6 post-mortem: serial / dbuf-drain0 / ring-counted on the 128^2
// 4-wave structure ALL land at 53us, MfmaUtil 18% - reproducing the guide's
// regime-gate null quadrant (T3/T4/T5 null outside the 8-phase structure).
// This is the verified structural jump instead: 8 waves (4Mx2N, 64x64/wave),
// BK=64, 3-tile LDS ring (144KB, 1 blk/CU), fully unrolled K-loop (static
// buffer indices), 2 phases/K-tile:
//   {8x ds_read_b128 | issue 3 gl_lds of tile t+2} -> s_barrier ->
//   lgkmcnt(0)+sched_barrier -> setprio(1) -> 16 MFMA -> setprio(0) ->
//   [tile end: vmcnt(6) - tile t+1 ready, t+2's 6 loads stay in flight,
//    NEVER drain to 0 mid-loop] -> s_barrier.
// Grid: QKV 64x12=768 blocks = 3 exact CU-rounds; O-proj 64x4 = 1 round.
// out[m,n] = sum_k A[m,k]*Bw[n,k] + bias[n].
// mode 0 (fused QKV, N=1536): seg0->out0 (Q), seg1->out1 (K), seg2->out2
//   (V TRANSPOSED [(b*8+h)*64+d][t]).  mode 1 (O-proj): out0, fp32 if *flagp.
__global__ __launch_bounds__(512, 2)
void gemm256(const u16* __restrict__ A, const u16* __restrict__ Bw,
             const u16* __restrict__ bias, void* __restrict__ out0,
             u16* __restrict__ out1, u16* __restrict__ out2,
             int mode, const int* __restrict__ flagp)
{
    __shared__ __align__(16) u16 AsF[3][256 * 64];   // 96 KB
    __shared__ __align__(16) u16 BsF[3][128 * 64];   // 48 KB (144 KB total, 1 blk/CU)

    const int tid  = threadIdx.x;
    const int lane = tid & 63;
    const int wv   = tid >> 6;          // 0..7
    const int col  = lane & 15;
    const int quad = lane >> 4;
    const int wm   = (wv >> 1) * 64;    // 0,64,128,192
    const int wn   = (wv & 1) * 64;     // 0,64
    const int m0   = blockIdx.x * 256;
    const int n0   = blockIdx.y * 128;

    f32x4 acc[4][4] = {};

    // staging: lane l covers row-in-group lr=l>>3, 16B slot lc=l&7;
    // source k-slot XOR-swizzled by row&7 (= lr, groups are 8-row-aligned).
    const int lr  = lane >> 3;
    const int lc  = lane & 7;
    const int cbs = lc ^ lr;

    // half 0: A groups {wv*4, wv*4+1} + B group wv*2
    // half 1: A groups {wv*4+2, wv*4+3} + B group wv*2+1   (6 gl_lds/wave/tile)
    auto STG = [&](int buf, int k0, int half) {
        #pragma unroll
        for (int i = 0; i < 2; i++) {
            const int g = wv * 4 + half * 2 + i;          // 0..31 (256 rows)
            gl_lds(A + (size_t)(m0 + g * 8 + lr) * 512 + k0 + cbs * 8,
                   &AsF[buf][g * 512]);
        }
        const int g2 = wv * 2 + half;                     // 0..15 (128 rows)
        gl_lds(Bw + (size_t)(n0 + g2 * 8 + lr) * 512 + k0 + cbs * 8,
               &BsF[buf][g2 * 512]);
    };

    // endw: -1 none, 6 counted, 0 drain (second-to-last tile only)
    auto PHASE = [&](int p, int kk, int q, int k2, int half, int dostage, int endw) {
        bf16x8 fa[4], fb[4];
        #pragma unroll
        for (int mi = 0; mi < 4; mi++)
            fa[mi] = ldsfrag(&AsF[p][(wm + mi * 16 + col) * 64 + ((kk * 4 + quad) ^ (col & 7)) * 8]);
        #pragma unroll
        for (int ni = 0; ni < 4; ni++)
            fb[ni] = ldsfrag(&BsF[p][(wn + ni * 16 + col) * 64 + ((kk * 4 + quad) ^ (col & 7)) * 8]);
        if (dostage) STG(q, k2, half);
        __builtin_amdgcn_s_barrier();
        asm volatile("s_waitcnt lgkmcnt(0)" ::: "memory");
        __builtin_amdgcn_sched_barrier(0);
        __builtin_amdgcn_s_setprio(1);
        #pragma unroll
        for (int mi = 0; mi < 4; mi++)
            #pragma unroll
            for (int ni = 0; ni < 4; ni++)
                acc[mi][ni] = mfma16(fa[mi], fb[ni], acc[mi][ni]);
        __builtin_amdgcn_s_setprio(0);
        if (endw == 6)      asm volatile("s_waitcnt vmcnt(6)" ::: "memory");
        else if (endw == 0) asm volatile("s_waitcnt vmcnt(0)" ::: "memory");
        __builtin_amdgcn_s_barrier();
        __builtin_amdgcn_sched_barrier(0);
    };

    // prologue: tiles 0,1 fully staged; wait tile 0 only (tile 1's 6 stay out)
    STG(0, 0, 0);  STG(0, 0, 1);
    STG(1, 64, 0); STG(1, 64, 1);
    asm volatile("s_waitcnt vmcnt(6)" ::: "memory");
    __builtin_amdgcn_s_barrier();
    __builtin_amdgcn_sched_barrier(0);

    #pragma unroll
    for (int t = 0; t < 8; t++) {                 // static after full unroll
        const int p  = t % 3;
        const int q  = (t + 2) % 3;
        const int k2 = (t + 2) * 64;
        const int st = (t < 6) ? 1 : 0;
        PHASE(p, 0, q, k2, 0, st, -1);
        PHASE(p, 1, q, k2, 1, st, (t < 6) ? 6 : ((t == 6) ? 0 : -1));
    }

    if (mode == 0) {
        #pragma unroll
        for (int ni = 0; ni < 4; ni++) {
            const int gn = n0 + wn + ni * 16 + col;     // 0..1535
            const float bv = b2f(bias[gn]);
            const int seg = gn >> 9;
            #pragma unroll
            for (int mi = 0; mi < 4; mi++) {
                const int gmb = m0 + wm + mi * 16 + quad * 4;
                if (seg < 2) {
                    u16* dst = (seg == 0) ? (u16*)out0 : out1;
                    #pragma unroll
                    for (int r = 0; r < 4; r++)
                        dst[(size_t)(gmb + r) * 512 + (gn & 511)] = f2b(acc[mi][ni][r] + bv);
                } else {
                    const int d = gn & 63, hh = (gn >> 6) & 7;
                    const int bb = gmb >> 13, t = gmb & 8191;
                    u16 pb[4];
                    #pragma unroll
                    for (int r = 0; r < 4; r++) pb[r] = f2b(acc[mi][ni][r] + bv);
                    uint2 pk;
                    pk.x = pb[0] | ((u32)pb[1] << 16);
                    pk.y = pb[2] | ((u32)pb[3] << 16);
                    *(uint2*)&out2[((size_t)(bb * 8 + hh) * 64 + d) * 8192 + t] = pk;
                }
            }
        }
    } else {
        const int outf32 = *flagp;
        #pragma unroll
        for (int ni = 0; ni < 4; ni++) {
            const int gn = n0 + wn + ni * 16 + col;
            const float bv = b2f(bias[gn]);
            #pragma unroll
            for (int mi = 0; mi < 4; mi++) {
                #pragma unroll
                for (int r = 0; r < 4; r++) {
                    const int gm = m0 + wm + mi * 16 + quad * 4 + r;
                    const float v = acc[mi][ni][r] + bv;
                    if (outf32) ((float*)out0)[(size_t)gm * 512 + gn] = v;
                    else        ((u16*)out0)[(size_t)gm * 512 + gn]  = f2b(v);
                }
            }
        }
    }
}

// Local attention, block = (b,h,chunk): 256 queries, 8 waves x 32 queries
// (512 threads). Double-buffered 64-key sub-chunks over [c-1,c,c+1];
// one barrier per iteration, prefetch in flight across compute.
// No max-subtraction (scores O(6), softmax shift-invariant).
// S^T = K.Q^T so P packs to LDS as b64; O^T = VT.P so normalization is
// per-lane and stores pack as 8B. V input is pre-transposed [b,h,d][t].
#define PSW 72
__global__ __launch_bounds__(512, 4)
void attn_local(const u16* __restrict__ Qg, const u16* __restrict__ Kg,
                const u16* __restrict__ VTg, u16* __restrict__ Og)
{
    __shared__ __align__(16) u16 Ks[2][64 * 64];   // 16 KB
    __shared__ __align__(16) u16 VTs[2][64 * 64];  // 16 KB
    __shared__ __align__(16) u16 Ps[8][32 * PSW];  // 36 KB (wave-private)

    const int tid  = threadIdx.x;
    const int lane = tid & 63;
    const int wv   = tid >> 6;          // 0..7
    const int col  = lane & 15;
    const int quad = lane >> 4;

    const int idx = blockIdx.x;
    const int c = idx & 31;
    const int h = (idx >> 5) & 7;
    const int b = idx >> 8;

    const int t0 = c * WW;
    const int wq = wv * 32;             // this wave's 32 queries

    const int sc_lo = (c == 0) ? 4 : 0;                 // kstart >= 0
    const int nsc   = (c == 0 || c == 31) ? 8 : 12;     // kstart < T

    const int ldr = lane >> 3;            // staging row-within-group (0..7)
    const int ldc = lane & 7;

    // Q fragments (B-operand): lane holds Q[t0+wq+qi*16+col][kk*32+quad*8..+8]
    bf16x8 qf[2][2];
    {
        const size_t qbase = ((size_t)(b * TT + t0 + wq + col)) * DD + h * DH + quad * 8;
        #pragma unroll
        for (int qi = 0; qi < 2; qi++)
            #pragma unroll
            for (int kk = 0; kk < 2; kk++)
                qf[qi][kk] = *(const bf16x8*)(Qg + qbase + (size_t)qi * 16 * DD + kk * 32);
    }

    f32x4 o[4][2] = {};                 // O^T accum: [di(d-tile)][qi(q-tile)]
    float lsum[2] = {0.f, 0.f};         // per-lane partial l for q=qi*16+col

    u16* psb = &Ps[wv][0];

    // prefetch first sub-chunk into buf 0 (one K + one VT row-group per wave)
    {
        const int kstart = t0 - WW + sc_lo * 64;
        const int rr = wv * 8 + ldr;
        const int cb = ldc ^ (rr & 7);
        gl_lds(Kg  + ((size_t)(b * TT + kstart + rr)) * DD + h * DH + cb * 8,
               &Ks[0][wv * 512]);
        gl_lds(VTg + ((size_t)((b * HH + h) * DH + rr)) * TT + kstart + cb * 8,
               &VTs[0][wv * 512]);
    }

    for (int it = 0; it < nsc; it++) {
        __syncthreads();   // drains loads for buf it&1; prev readers of other buf done
        if (it + 1 < nsc) {
            const int kstart = t0 - WW + (sc_lo + it + 1) * 64;
            const int buf = (it + 1) & 1;
            const int rr = wv * 8 + ldr;
            const int cb = ldc ^ (rr & 7);
            gl_lds(Kg  + ((size_t)(b * TT + kstart + rr)) * DD + h * DH + cb * 8,
                   &Ks[buf][wv * 512]);
            gl_lds(VTg + ((size_t)((b * HH + h) * DH + rr)) * TT + kstart + cb * 8,
                   &VTs[buf][wv * 512]);
        }
        const u16* ks = &Ks[it & 1][0];
        const u16* vs = &VTs[it & 1][0];

        // S^T[key][q] : A = K rows, B = Q rows (32 queries per wave)
        f32x4 s[4][2];
        #pragma unroll
        for (int ns = 0; ns < 4; ns++)
            #pragma unroll
            for (int qi = 0; qi < 2; qi++)
                s[ns][qi] = (f32x4){0.f, 0.f, 0.f, 0.f};
        #pragma unroll
        for (int ns = 0; ns < 4; ns++) {
            const int row = ns * 16 + col;
            bf16x8 ka0 = ldsfrag(&ks[row * 64 + ((0 + quad) ^ (col & 7)) * 8]);
            bf16x8 ka1 = ldsfrag(&ks[row * 64 + ((4 + quad) ^ (col & 7)) * 8]);
            #pragma unroll
            for (int qi = 0; qi < 2; qi++) {
                s[ns][qi] = mfma16(ka0, qf[qi][0], s[ns][qi]);
                s[ns][qi] = mfma16(ka1, qf[qi][1], s[ns][qi]);
            }
        }

        // p = exp(s/8), accumulate l (fp32, pre-rounding), pack -> b64 write
        #pragma unroll
        for (int ns = 0; ns < 4; ns++) {
            #pragma unroll
            for (int qi = 0; qi < 2; qi++) {
                u16 pb[4];
                #pragma unroll
                for (int r = 0; r < 4; r++) {
                    const float p = __expf(s[ns][qi][r] * 0.125f);
                    pb[r] = f2b(p);
                    lsum[qi] += p;
                }
                uint2 pk;
                pk.x = pb[0] | ((u32)pb[1] << 16);
                pk.y = pb[2] | ((u32)pb[3] << 16);
                *(uint2*)&psb[(qi * 16 + col) * PSW + ns * 16 + quad * 4] = pk;
            }
        }
        asm volatile("" ::: "memory");   // order Ps write -> read (wave-private)

        // O^T += VT . P : A = VT (m=d), B = Ps rows (n=q)
        #pragma unroll
        for (int kt = 0; kt < 2; kt++) {
            bf16x8 pf[2];
            #pragma unroll
            for (int qi = 0; qi < 2; qi++)
                pf[qi] = ldsfrag(&psb[(qi * 16 + col) * PSW + kt * 32 + quad * 8]);
            #pragma unroll
            for (int di = 0; di < 4; di++) {
                bf16x8 va = ldsfrag(&vs[(di * 16 + col) * 64 + ((kt * 4 + quad) ^ (col & 7)) * 8]);
                #pragma unroll
                for (int qi = 0; qi < 2; qi++)
                    o[di][qi] = mfma16(va, pf[qi], o[di][qi]);
            }
        }
    }

    // final l reduction over quads (lanes col,col+16,col+32,col+48 share q)
    #pragma unroll
    for (int qi = 0; qi < 2; qi++) {
        float l = lsum[qi];
        l += __shfl_xor(l, 16);
        l += __shfl_xor(l, 32);
        lsum[qi] = 1.0f / l;
    }

    // store O^T: element (di,qi,r): d = di*16+quad*4+r, q = qi*16+col
    #pragma unroll
    for (int qi = 0; qi < 2; qi++) {
        const size_t ob = ((size_t)(b * TT + t0 + wq + qi * 16 + col)) * DD + h * DH + quad * 4;
        #pragma unroll
        for (int di = 0; di < 4; di++) {
            u16 pb[4];
            #pragma unroll
            for (int r = 0; r < 4; r++) pb[r] = f2b(o[di][qi][r] * lsum[qi]);
            uint2 pk;
            pk.x = pb[0] | ((u32)pb[1] << 16);
            pk.y = pb[2] | ((u32)pb[3] << 16);
            *(uint2*)&Og[ob + di * 16] = pk;
        }
    }
}

extern "C" void kernel_launch(void* const* d_in, const int* in_sizes, int n_in,
                              void* d_out, int out_size, void* d_ws, size_t ws_size,
                              hipStream_t stream)
{
    u16* ws   = (u16*)d_ws;
    u16* xb   = ws;                       // NX
    u16* Wcat = xb + NX;                  // 3*NW  (Wq,Wk,Wv rows concatenated)
    u16* Wob  = Wcat + 3 * NW;            // NW
    u16* bcat = Wob + NW;                 // 1536
    u16* bob  = bcat + 1536;              // 512
    u16* qws  = bob + 512;                // NX   Q  [b*T+t][h*64+d]
    u16* kws  = qws + NX;                 // NX   K  same
    u16* vtws = kws + NX;                 // NX   V^T [(b*8+h)*64+d][t]
    u16* aws  = vtws + NX;                // NX   attn out [b*T+t][h*64+d]
    int* flag = (int*)(aws + NX);

    // 9439232 elements / 8 per thread / 256 per block = 4609 blocks
    convert_all<<<4609, 256, 0, stream>>>(
        d_in[0], d_in[1], d_in[2], d_in[3], d_in[4], d_in[5], d_in[6], d_in[7], d_in[8],
        xb, Wcat, Wob, bcat, bob, flag);

    // fused QKV projection: N = 1536, 256x128 tiles -> 64x12 = 768 blocks
    gemm256<<<dim3(64, 12), 512, 0, stream>>>(xb, Wcat, bcat, qws, kws, vtws, 0, flag);
    // local attention: 512 blocks x 512 threads
    attn_local<<<dim3(BB * HH * 32), 512, 0, stream>>>(qws, kws, vtws, aws);
    // output projection: 64x4 = 256 blocks = 1 exact round
    gemm256<<<dim3(64, 4), 512, 0, stream>>>(aws, Wob, bob, d_out, nullptr, nullptr, 1, flag);
}

// Round 8
// 190.136 us; speedup vs baseline: 1.0765x; 1.0152x over previous
//
#include <hip/hip_runtime.h>
#include <hip/hip_bf16.h>

typedef unsigned short u16;
typedef unsigned int   u32;
typedef __bf16 bf16x8 __attribute__((ext_vector_type(8)));
typedef float  f32x4  __attribute__((ext_vector_type(4)));

#define BB 2
#define TT 8192
#define DD 512
#define HH 8
#define WW 256
#define DH 64
#define NX 8388608   // 16384*512
#define NW 262144    // 512*512

__device__ __forceinline__ float b2f(u16 u) {
    unsigned int x = ((unsigned int)u) << 16;
    return __builtin_bit_cast(float, x);
}
__device__ __forceinline__ u16 f2b(float f) {
    __bf16 h = (__bf16)f;
    return __builtin_bit_cast(u16, h);
}
__device__ __forceinline__ bf16x8 ldsfrag(const u16* p) {
    return *(const bf16x8*)p;
}
__device__ __forceinline__ f32x4 mfma16(bf16x8 a, bf16x8 b, f32x4 c) {
    return __builtin_amdgcn_mfma_f32_16x16x32_bf16(a, b, c, 0, 0, 0);
}

typedef __attribute__((address_space(1))) u32 gu32;
typedef __attribute__((address_space(3))) u32 lu32;
// async global->LDS, 16B per lane, dest = wave-uniform base + lane*16
__device__ __forceinline__ void gl_lds(const u16* g, u16* l) {
    __builtin_amdgcn_global_load_lds((gu32*)g, (lu32*)l, 16, 0, 0);
}

// ---- convert all 9 inputs to bf16 in workspace (vectorized, 8 elem/thread).
__device__ __forceinline__ void cvt8(const void* s, u16* d, long i, int f) {
    if (f) {
        const u32* sp = (const u32*)s + i;
        uint4 a = *(const uint4*)(sp);
        uint4 b = *(const uint4*)(sp + 4);
        u16 o[8];
        o[0] = f2b(__builtin_bit_cast(float, a.x));
        o[1] = f2b(__builtin_bit_cast(float, a.y));
        o[2] = f2b(__builtin_bit_cast(float, a.z));
        o[3] = f2b(__builtin_bit_cast(float, a.w));
        o[4] = f2b(__builtin_bit_cast(float, b.x));
        o[5] = f2b(__builtin_bit_cast(float, b.y));
        o[6] = f2b(__builtin_bit_cast(float, b.z));
        o[7] = f2b(__builtin_bit_cast(float, b.w));
        *(uint4*)(d + i) = *(const uint4*)o;
    } else {
        *(uint4*)(d + i) = *(const uint4*)((const u16*)s + i);
    }
}

__global__ void convert_all(const void* x, const void* Wq, const void* bq,
                            const void* Wk, const void* bk, const void* Wv,
                            const void* bv, const void* Wo, const void* bo,
                            u16* __restrict__ xb, u16* __restrict__ Wcat,
                            u16* __restrict__ Wob, u16* __restrict__ bcat,
                            u16* __restrict__ bob, int* __restrict__ flagw)
{
    __shared__ int sflag;
    const int tid = threadIdx.x;
    if (tid == 0) sflag = 0;
    __syncthreads();
    int mybad = 0;
    for (int i = tid; i < 2048; i += 256) {
        float v = b2f(((const u16*)x)[i]);
        if (!(fabsf(v) < 100.f)) mybad = 1;   // fp32 mantissa halves look wild
    }
    if (mybad) atomicOr(&sflag, 1);
    __syncthreads();
    const int f = sflag ? 1 : 0;
    if (blockIdx.x == 0 && tid == 0) *flagw = f;

    long i = ((long)blockIdx.x * 256 + tid) * 8;
    if (i < NX)            { cvt8(x,  xb,           i, f); return; }
    i -= NX;
    if (i < NW)            { cvt8(Wq, Wcat,         i, f); return; }
    i -= NW;
    if (i < NW)            { cvt8(Wk, Wcat + NW,    i, f); return; }
    i -= NW;
    if (i < NW)            { cvt8(Wv, Wcat + 2*NW,  i, f); return; }
    i -= NW;
    if (i < NW)            { cvt8(Wo, Wob,          i, f); return; }
    i -= NW;
    if (i < 512)           { cvt8(bq, bcat,         i, f); return; }
    i -= 512;
    if (i < 512)           { cvt8(bk, bcat + 512,   i, f); return; }
    i -= 512;
    if (i < 512)           { cvt8(bv, bcat + 1024,  i, f); return; }
    i -= 512;
    if (i < 512)           { cvt8(bo, bob,          i, f); }
}

// 256x128-tile GEMM, K=512. Round-9: round-7 schedule + occupancy.
// Round-7 post-mortem: the phased structure at 144KB LDS ran 1 blk/CU
// (2 waves/SIMD) - occupancy fell to 17.8% and the schedule had nothing
// to overlap stalls with; MfmaUtil stuck at 20%. Cross-round invariant:
// all variants converge to ~40k cyc per CU-round, LDS-read service +
// barrier convoys + load waits unhidden at low wave count.
// This round: BK 64->32 shrinks the 3-tile ring to 72KB -> 2 blocks/CU,
// 16 waves/CU (4/SIMD): cross-block overlap hides barrier/vmcnt stalls.
// Also 1 barrier per phase (pre-MFMA barrier provably redundant with a
// 3-ring: phase t writes buf t+2, last read in phase t-1 behind its own
// end-barrier), halving convoys to 16. Counted vmcnt(3): 3 stage-loads
// per wave per tile; end of phase t has 6 outstanding -> wait 3 => tile
// t+1 landed, t+2's 3 stay in flight. Never drain mid-loop.
// out[m,n] = sum_k A[m,k]*Bw[n,k] + bias[n].
// mode 0 (fused QKV, N=1536): seg0->out0 (Q), seg1->out1 (K), seg2->out2
//   (V TRANSPOSED [(b*8+h)*64+d][t]).  mode 1 (O-proj): out0, fp32 if *flagp.
__global__ __launch_bounds__(512, 4)
void gemm256(const u16* __restrict__ A, const u16* __restrict__ Bw,
             const u16* __restrict__ bias, void* __restrict__ out0,
             u16* __restrict__ out1, u16* __restrict__ out2,
             int mode, const int* __restrict__ flagp)
{
    __shared__ __align__(16) u16 AsF[3][256 * 32];   // 48 KB
    __shared__ __align__(16) u16 BsF[3][128 * 32];   // 24 KB (72 KB -> 2 blk/CU)

    const int tid  = threadIdx.x;
    const int lane = tid & 63;
    const int wv   = tid >> 6;          // 0..7
    const int col  = lane & 15;
    const int quad = lane >> 4;
    const int wm   = (wv >> 1) * 64;    // 0,64,128,192
    const int wn   = (wv & 1) * 64;     // 0,64
    const int m0   = blockIdx.x * 256;
    const int n0   = blockIdx.y * 128;

    f32x4 acc[4][4] = {};

    // staging (BK=32): one gl_lds = 16 rows x 64B. lane l -> row l>>2,
    // 16B slot l&3; source k-slot XOR-swizzled by row&3.
    const int sr  = lane >> 2;          // row within 16-row group
    const int cbs = (lane & 3) ^ (sr & 3);

    // per wave per tile: 2 A-groups + 1 B-group = 3 gl_lds
    auto STG = [&](int buf, int k0) {
        #pragma unroll
        for (int i = 0; i < 2; i++) {
            const int g = wv * 2 + i;                 // 0..15 (256 rows)
            gl_lds(A + (size_t)(m0 + g * 16 + sr) * 512 + k0 + cbs * 8,
                   &AsF[buf][g * 512]);
        }
        gl_lds(Bw + (size_t)(n0 + wv * 16 + sr) * 512 + k0 + cbs * 8,
               &BsF[buf][wv * 512]);
    };

    // read slot: row = wm/wn + mi*16 + col -> row&3 == col&3
    const int rdo = (quad ^ (col & 3)) * 8;

    // prologue: tiles 0,1 staged (6/wave); wait 3 => tile 0 landed
    STG(0, 0);
    STG(1, 32);
    asm volatile("s_waitcnt vmcnt(3)" ::: "memory");
    __builtin_amdgcn_s_barrier();
    __builtin_amdgcn_sched_barrier(0);

    #pragma unroll
    for (int t = 0; t < 16; t++) {                // static after full unroll
        const int p = t % 3;
        bf16x8 fa[4], fb[4];
        #pragma unroll
        for (int mi = 0; mi < 4; mi++)
            fa[mi] = ldsfrag(&AsF[p][(wm + mi * 16 + col) * 32 + rdo]);
        #pragma unroll
        for (int ni = 0; ni < 4; ni++)
            fb[ni] = ldsfrag(&BsF[p][(wn + ni * 16 + col) * 32 + rdo]);
        if (t < 14) STG((t + 2) % 3, (t + 2) * 32);
        __builtin_amdgcn_s_setprio(1);
        #pragma unroll
        for (int mi = 0; mi < 4; mi++)
            #pragma unroll
            for (int ni = 0; ni < 4; ni++)
                acc[mi][ni] = mfma16(fa[mi], fb[ni], acc[mi][ni]);
        __builtin_amdgcn_s_setprio(0);
        if (t < 14) {
            // tile t+1 landed; tile t+2's 3 loads stay in flight
            asm volatile("s_waitcnt vmcnt(3)" ::: "memory");
            __builtin_amdgcn_s_barrier();
            __builtin_amdgcn_sched_barrier(0);
        } else if (t == 14) {
            asm volatile("s_waitcnt vmcnt(0)" ::: "memory");
            __builtin_amdgcn_s_barrier();
            __builtin_amdgcn_sched_barrier(0);
        }
    }

    if (mode == 0) {
        #pragma unroll
        for (int ni = 0; ni < 4; ni++) {
            const int gn = n0 + wn + ni * 16 + col;     // 0..1535
            const float bv = b2f(bias[gn]);
            const int seg = gn >> 9;
            #pragma unroll
            for (int mi = 0; mi < 4; mi++) {
                const int gmb = m0 + wm + mi * 16 + quad * 4;
                if (seg < 2) {
                    u16* dst = (seg == 0) ? (u16*)out0 : out1;
                    #pragma unroll
                    for (int r = 0; r < 4; r++)
                        dst[(size_t)(gmb + r) * 512 + (gn & 511)] = f2b(acc[mi][ni][r] + bv);
                } else {
                    const int d = gn & 63, hh = (gn >> 6) & 7;
                    const int bb = gmb >> 13, t = gmb & 8191;
                    u16 pb[4];
                    #pragma unroll
                    for (int r = 0; r < 4; r++) pb[r] = f2b(acc[mi][ni][r] + bv);
                    uint2 pk;
                    pk.x = pb[0] | ((u32)pb[1] << 16);
                    pk.y = pb[2] | ((u32)pb[3] << 16);
                    *(uint2*)&out2[((size_t)(bb * 8 + hh) * 64 + d) * 8192 + t] = pk;
                }
            }
        }
    } else {
        const int outf32 = *flagp;
        #pragma unroll
        for (int ni = 0; ni < 4; ni++) {
            const int gn = n0 + wn + ni * 16 + col;
            const float bv = b2f(bias[gn]);
            #pragma unroll
            for (int mi = 0; mi < 4; mi++) {
                #pragma unroll
                for (int r = 0; r < 4; r++) {
                    const int gm = m0 + wm + mi * 16 + quad * 4 + r;
                    const float v = acc[mi][ni][r] + bv;
                    if (outf32) ((float*)out0)[(size_t)gm * 512 + gn] = v;
                    else        ((u16*)out0)[(size_t)gm * 512 + gn]  = f2b(v);
                }
            }
        }
    }
}

// Local attention, block = (b,h,chunk): 256 queries, 8 waves x 32 queries
// (512 threads). Double-buffered 64-key sub-chunks over [c-1,c,c+1];
// one barrier per iteration, prefetch in flight across compute.
// No max-subtraction (scores O(6), softmax shift-invariant).
// S^T = K.Q^T so P packs to LDS as b64; O^T = VT.P so normalization is
// per-lane and stores pack as 8B. V input is pre-transposed [b,h,d][t].
#define PSW 72
__global__ __launch_bounds__(512, 4)
void attn_local(const u16* __restrict__ Qg, const u16* __restrict__ Kg,
                const u16* __restrict__ VTg, u16* __restrict__ Og)
{
    __shared__ __align__(16) u16 Ks[2][64 * 64];   // 16 KB
    __shared__ __align__(16) u16 VTs[2][64 * 64];  // 16 KB
    __shared__ __align__(16) u16 Ps[8][32 * PSW];  // 36 KB (wave-private)

    const int tid  = threadIdx.x;
    const int lane = tid & 63;
    const int wv   = tid >> 6;          // 0..7
    const int col  = lane & 15;
    const int quad = lane >> 4;

    const int idx = blockIdx.x;
    const int c = idx & 31;
    const int h = (idx >> 5) & 7;
    const int b = idx >> 8;

    const int t0 = c * WW;
    const int wq = wv * 32;             // this wave's 32 queries

    const int sc_lo = (c == 0) ? 4 : 0;                 // kstart >= 0
    const int nsc   = (c == 0 || c == 31) ? 8 : 12;     // kstart < T

    const int ldr = lane >> 3;            // staging row-within-group (0..7)
    const int ldc = lane & 7;

    // Q fragments (B-operand): lane holds Q[t0+wq+qi*16+col][kk*32+quad*8..+8]
    bf16x8 qf[2][2];
    {
        const size_t qbase = ((size_t)(b * TT + t0 + wq + col)) * DD + h * DH + quad * 8;
        #pragma unroll
        for (int qi = 0; qi < 2; qi++)
            #pragma unroll
            for (int kk = 0; kk < 2; kk++)
                qf[qi][kk] = *(const bf16x8*)(Qg + qbase + (size_t)qi * 16 * DD + kk * 32);
    }

    f32x4 o[4][2] = {};                 // O^T accum: [di(d-tile)][qi(q-tile)]
    float lsum[2] = {0.f, 0.f};         // per-lane partial l for q=qi*16+col

    u16* psb = &Ps[wv][0];

    // prefetch first sub-chunk into buf 0 (one K + one VT row-group per wave)
    {
        const int kstart = t0 - WW + sc_lo * 64;
        const int rr = wv * 8 + ldr;
        const int cb = ldc ^ (rr & 7);
        gl_lds(Kg  + ((size_t)(b * TT + kstart + rr)) * DD + h * DH + cb * 8,
               &Ks[0][wv * 512]);
        gl_lds(VTg + ((size_t)((b * HH + h) * DH + rr)) * TT + kstart + cb * 8,
               &VTs[0][wv * 512]);
    }

    for (int it = 0; it < nsc; it++) {
        __syncthreads();   // drains loads for buf it&1; prev readers of other buf done
        if (it + 1 < nsc) {
            const int kstart = t0 - WW + (sc_lo + it + 1) * 64;
            const int buf = (it + 1) & 1;
            const int rr = wv * 8 + ldr;
            const int cb = ldc ^ (rr & 7);
            gl_lds(Kg  + ((size_t)(b * TT + kstart + rr)) * DD + h * DH + cb * 8,
                   &Ks[buf][wv * 512]);
            gl_lds(VTg + ((size_t)((b * HH + h) * DH + rr)) * TT + kstart + cb * 8,
                   &VTs[buf][wv * 512]);
        }
        const u16* ks = &Ks[it & 1][0];
        const u16* vs = &VTs[it & 1][0];

        // S^T[key][q] : A = K rows, B = Q rows (32 queries per wave)
        f32x4 s[4][2];
        #pragma unroll
        for (int ns = 0; ns < 4; ns++)
            #pragma unroll
            for (int qi = 0; qi < 2; qi++)
                s[ns][qi] = (f32x4){0.f, 0.f, 0.f, 0.f};
        #pragma unroll
        for (int ns = 0; ns < 4; ns++) {
            const int row = ns * 16 + col;
            bf16x8 ka0 = ldsfrag(&ks[row * 64 + ((0 + quad) ^ (col & 7)) * 8]);
            bf16x8 ka1 = ldsfrag(&ks[row * 64 + ((4 + quad) ^ (col & 7)) * 8]);
            #pragma unroll
            for (int qi = 0; qi < 2; qi++) {
                s[ns][qi] = mfma16(ka0, qf[qi][0], s[ns][qi]);
                s[ns][qi] = mfma16(ka1, qf[qi][1], s[ns][qi]);
            }
        }

        // p = exp(s/8), accumulate l (fp32, pre-rounding), pack -> b64 write
        #pragma unroll
        for (int ns = 0; ns < 4; ns++) {
            #pragma unroll
            for (int qi = 0; qi < 2; qi++) {
                u16 pb[4];
                #pragma unroll
                for (int r = 0; r < 4; r++) {
                    const float p = __expf(s[ns][qi][r] * 0.125f);
                    pb[r] = f2b(p);
                    lsum[qi] += p;
                }
                uint2 pk;
                pk.x = pb[0] | ((u32)pb[1] << 16);
                pk.y = pb[2] | ((u32)pb[3] << 16);
                *(uint2*)&psb[(qi * 16 + col) * PSW + ns * 16 + quad * 4] = pk;
            }
        }
        asm volatile("" ::: "memory");   // order Ps write -> read (wave-private)

        // O^T += VT . P : A = VT (m=d), B = Ps rows (n=q)
        #pragma unroll
        for (int kt = 0; kt < 2; kt++) {
            bf16x8 pf[2];
            #pragma unroll
            for (int qi = 0; qi < 2; qi++)
                pf[qi] = ldsfrag(&psb[(qi * 16 + col) * PSW + kt * 32 + quad * 8]);
            #pragma unroll
            for (int di = 0; di < 4; di++) {
                bf16x8 va = ldsfrag(&vs[(di * 16 + col) * 64 + ((kt * 4 + quad) ^ (col & 7)) * 8]);
                #pragma unroll
                for (int qi = 0; qi < 2; qi++)
                    o[di][qi] = mfma16(va, pf[qi], o[di][qi]);
            }
        }
    }

    // final l reduction over quads (lanes col,col+16,col+32,col+48 share q)
    #pragma unroll
    for (int qi = 0; qi < 2; qi++) {
        float l = lsum[qi];
        l += __shfl_xor(l, 16);
        l += __shfl_xor(l, 32);
        lsum[qi] = 1.0f / l;
    }

    // store O^T: element (di,qi,r): d = di*16+quad*4+r, q = qi*16+col
    #pragma unroll
    for (int qi = 0; qi < 2; qi++) {
        const size_t ob = ((size_t)(b * TT + t0 + wq + qi * 16 + col)) * DD + h * DH + quad * 4;
        #pragma unroll
        for (int di = 0; di < 4; di++) {
            u16 pb[4];
            #pragma unroll
            for (int r = 0; r < 4; r++) pb[r] = f2b(o[di][qi][r] * lsum[qi]);
            uint2 pk;
            pk.x = pb[0] | ((u32)pb[1] << 16);
            pk.y = pb[2] | ((u32)pb[3] << 16);
            *(uint2*)&Og[ob + di * 16] = pk;
        }
    }
}

extern "C" void kernel_launch(void* const* d_in, const int* in_sizes, int n_in,
                              void* d_out, int out_size, void* d_ws, size_t ws_size,
                              hipStream_t stream)
{
    u16* ws   = (u16*)d_ws;
    u16* xb   = ws;                       // NX
    u16* Wcat = xb + NX;                  // 3*NW  (Wq,Wk,Wv rows concatenated)
    u16* Wob  = Wcat + 3 * NW;            // NW
    u16* bcat = Wob + NW;                 // 1536
    u16* bob  = bcat + 1536;              // 512
    u16* qws  = bob + 512;                // NX   Q  [b*T+t][h*64+d]
    u16* kws  = qws + NX;                 // NX   K  same
    u16* vtws = kws + NX;                 // NX   V^T [(b*8+h)*64+d][t]
    u16* aws  = vtws + NX;                // NX   attn out [b*T+t][h*64+d]
    int* flag = (int*)(aws + NX);

    // 9439232 elements / 8 per thread / 256 per block = 4609 blocks
    convert_all<<<4609, 256, 0, stream>>>(
        d_in[0], d_in[1], d_in[2], d_in[3], d_in[4], d_in[5], d_in[6], d_in[7], d_in[8],
        xb, Wcat, Wob, bcat, bob, flag);

    // fused QKV projection: N = 1536, 256x128 tiles -> 64x12 = 768 blocks (2/CU)
    gemm256<<<dim3(64, 12), 512, 0, stream>>>(xb, Wcat, bcat, qws, kws, vtws, 0, flag);
    // local attention: 512 blocks x 512 threads
    attn_local<<<dim3(BB * HH * 32), 512, 0, stream>>>(qws, kws, vtws, aws);
    // output projection: 64x4 = 256 blocks, all co-resident
    gemm256<<<dim3(64, 4), 512, 0, stream>>>(aws, Wob, bob, d_out, nullptr, nullptr, 1, flag);
}